// Round 1
// baseline (4983.657 us; speedup 1.0000x reference)
//
#include <hip/hip_runtime.h>
#include <math.h>

#define BB 4
#define NN 2048
#define DD 64
#define PP 8192
#define NSTRIPE 512

__global__ void zero_ws_kernel(float* ws) {
    int t = blockIdx.x * blockDim.x + threadIdx.x;
    if (t < BB * NSTRIPE) ws[t] = 0.f;
}

__global__ __launch_bounds__(256) void swd_kernel(const float* __restrict__ x,
                                                  const float* __restrict__ y,
                                                  const float* __restrict__ proj,
                                                  float* __restrict__ ws) {
    __shared__ float sp1[NN];
    __shared__ float sp2[NN];
    __shared__ float prj[DD];
    __shared__ float red[8];

    const int tid = threadIdx.x;
    const int bid = blockIdx.x;
    const int b = bid >> 13;        // bid / P  (8192 blocks per batch -> x[b] stays L2-hot)
    const int p = bid & (PP - 1);

    if (tid < DD) prj[tid] = proj[(size_t)p * DD + tid];
    __syncthreads();

    // ---- projection: each thread computes 8 rows (r = tid + 256*i) for both x and y
    const float4* prj4 = (const float4*)prj;
    const float4* xb = (const float4*)(x + (size_t)b * NN * DD);
    const float4* yb = (const float4*)(y + (size_t)b * NN * DD);
    #pragma unroll
    for (int i = 0; i < 8; i++) {
        int r = tid + (i << 8);
        const float4* xr = xb + r * (DD / 4);
        const float4* yr = yb + r * (DD / 4);
        float s1 = 0.f, s2 = 0.f;
        #pragma unroll
        for (int d = 0; d < DD / 4; d++) {
            float4 pv = prj4[d];          // LDS broadcast (uniform address)
            float4 xv = xr[d];
            s1 += xv.x * pv.x + xv.y * pv.y + xv.z * pv.z + xv.w * pv.w;
            float4 yv = yr[d];
            s2 += yv.x * pv.x + yv.y * pv.y + yv.z * pv.z + yv.w * pv.w;
        }
        sp1[r] = s1;
        sp2[r] = s2;
    }

    // ---- bitonic sort both columns ascending (classic network, pair-index compressed)
    for (int k = 2; k <= NN; k <<= 1) {
        for (int j = k >> 1; j > 0; j >>= 1) {
            __syncthreads();
            #pragma unroll 1
            for (int s = 0; s < 4; s++) {
                int pr = tid + (s << 8);                      // pair index 0..1023
                int i  = ((pr & ~(j - 1)) << 1) | (pr & (j - 1));
                int ixj = i | j;
                bool up = ((i & k) == 0);
                float a0 = sp1[i], a1 = sp1[ixj];
                if ((a0 > a1) == up) { sp1[i] = a1; sp1[ixj] = a0; }
                float b0 = sp2[i], b1 = sp2[ixj];
                if ((b0 > b1) == up) { sp2[i] = b1; sp2[ixj] = b0; }
            }
        }
    }
    __syncthreads();

    // ---- sum of squared diffs of sorted columns
    float lsum = 0.f;
    #pragma unroll
    for (int i = 0; i < 8; i++) {
        int r = tid + (i << 8);
        float d0 = sp1[r] - sp2[r];
        lsum += d0 * d0;
    }
    #pragma unroll
    for (int off = 32; off > 0; off >>= 1)
        lsum += __shfl_down(lsum, off, 64);
    int wave = tid >> 6;
    if ((tid & 63) == 0) red[wave] = lsum;
    __syncthreads();
    if (tid == 0) {
        float t = red[0] + red[1] + red[2] + red[3];
        atomicAdd(&ws[b * NSTRIPE + (bid & (NSTRIPE - 1))], t);
    }
}

__global__ void finalize_kernel(const float* __restrict__ ws, float* __restrict__ out) {
    __shared__ float red[256];
    int tid = threadIdx.x;
    for (int b = 0; b < BB; b++) {
        float s = 0.f;
        for (int i = tid; i < NSTRIPE; i += 256) s += ws[b * NSTRIPE + i];
        red[tid] = s;
        __syncthreads();
        for (int o = 128; o > 0; o >>= 1) {
            if (tid < o) red[tid] += red[tid + o];
            __syncthreads();
        }
        if (tid == 0) {
            float swd = red[0] / ((float)NN * (float)PP);
            out[b] = expf(-swd * swd * 0.5f);
        }
        __syncthreads();
    }
}

extern "C" void kernel_launch(void* const* d_in, const int* in_sizes, int n_in,
                              void* d_out, int out_size, void* d_ws, size_t ws_size,
                              hipStream_t stream) {
    const float* x = (const float*)d_in[0];
    const float* y = (const float*)d_in[1];
    const float* proj = (const float*)d_in[2];
    float* out = (float*)d_out;
    float* ws = (float*)d_ws;

    zero_ws_kernel<<<(BB * NSTRIPE + 255) / 256, 256, 0, stream>>>(ws);
    swd_kernel<<<BB * PP, 256, 0, stream>>>(x, y, proj, ws);
    finalize_kernel<<<1, 256, 0, stream>>>(ws, out);
}

// Round 2
// 4301.779 us; speedup vs baseline: 1.1585x; 1.1585x over previous
//
#include <hip/hip_runtime.h>
#include <math.h>

#define BB 4
#define NN 2048
#define DD 64
#define PP 8192
#define NSTRIPE 512

__global__ void zero_ws_kernel(float* ws) {
    int t = blockIdx.x * blockDim.x + threadIdx.x;
    if (t < BB * NSTRIPE) ws[t] = 0.f;
}

__device__ __forceinline__ void ce_dir(float& a, float& b, bool up) {
    float lo = fminf(a, b);
    float hi = fmaxf(a, b);
    a = up ? lo : hi;
    b = up ? hi : lo;
}

__global__ __launch_bounds__(256) void swd_kernel(const float* __restrict__ x,
                                                  const float* __restrict__ y,
                                                  const float* __restrict__ proj,
                                                  float* __restrict__ ws) {
    __shared__ float s1[NN];
    __shared__ float s2[NN];
    __shared__ float prj[DD];
    __shared__ float red[8];

    const int tid = threadIdx.x;
    const int bid = blockIdx.x;
    const int b = bid >> 13;          // 8192 consecutive blocks share x[b],y[b] (L2-hot)
    const int p = bid & (PP - 1);

    if (tid < DD) prj[tid] = proj[(size_t)p * DD + tid];
    __syncthreads();

    // ---- projection straight into blocked register layout: thread owns rows 8t..8t+7
    float e1[8], e2[8];
    const float4* prj4 = (const float4*)prj;
    const float4* xb = (const float4*)(x + (size_t)b * NN * DD);
    const float4* yb = (const float4*)(y + (size_t)b * NN * DD);
    const int base = tid << 3;
    #pragma unroll
    for (int v = 0; v < 8; v++) {
        const float4* xr = xb + (size_t)(base + v) * (DD / 4);
        const float4* yr = yb + (size_t)(base + v) * (DD / 4);
        float a1 = 0.f, a2 = 0.f;
        #pragma unroll
        for (int d = 0; d < DD / 4; d++) {
            float4 pv = prj4[d];              // LDS broadcast
            float4 xv = xr[d];
            a1 += xv.x * pv.x + xv.y * pv.y + xv.z * pv.z + xv.w * pv.w;
            float4 yv = yr[d];
            a2 += yv.x * pv.x + yv.y * pv.y + yv.z * pv.z + yv.w * pv.w;
        }
        e1[v] = a1;
        e2[v] = a2;
    }

    // ---- bitonic sort, element i = 8*tid + v, ascending overall
    // k = 2  (dir = ((i&2)==0) -> depends on v)
    ce_dir(e1[0], e1[1], true);  ce_dir(e1[2], e1[3], false);
    ce_dir(e1[4], e1[5], true);  ce_dir(e1[6], e1[7], false);
    ce_dir(e2[0], e2[1], true);  ce_dir(e2[2], e2[3], false);
    ce_dir(e2[4], e2[5], true);  ce_dir(e2[6], e2[7], false);
    // k = 4, j = 2  (dir = ((i&4)==0) -> v<4 up, else down)
    ce_dir(e1[0], e1[2], true);  ce_dir(e1[1], e1[3], true);
    ce_dir(e1[4], e1[6], false); ce_dir(e1[5], e1[7], false);
    ce_dir(e2[0], e2[2], true);  ce_dir(e2[1], e2[3], true);
    ce_dir(e2[4], e2[6], false); ce_dir(e2[5], e2[7], false);
    // k = 4, j = 1
    ce_dir(e1[0], e1[1], true);  ce_dir(e1[2], e1[3], true);
    ce_dir(e1[4], e1[5], false); ce_dir(e1[6], e1[7], false);
    ce_dir(e2[0], e2[1], true);  ce_dir(e2[2], e2[3], true);
    ce_dir(e2[4], e2[5], false); ce_dir(e2[6], e2[7], false);

    #pragma unroll
    for (int k = 8; k <= NN; k <<= 1) {
        const bool up = ((base & k) == 0);            // uniform per thread (k >= 8)
        #pragma unroll
        for (int j = k >> 1; j >= 8; j >>= 1) {
            const int lm = j >> 3;                    // thread-xor distance
            const bool keepmin = (up == ((tid & lm) == 0));
            if (lm < 64) {
                // in-wave exchange via permute network (no bank conflicts)
                #pragma unroll
                for (int v = 0; v < 8; v++) {
                    float pv = __shfl_xor(e1[v], lm, 64);
                    e1[v] = keepmin ? fminf(e1[v], pv) : fmaxf(e1[v], pv);
                    float qv = __shfl_xor(e2[v], lm, 64);
                    e2[v] = keepmin ? fminf(e2[v], qv) : fmaxf(e2[v], qv);
                }
            } else {
                // cross-wave exchange through LDS (only j=512,1024: 3 passes total)
                __syncthreads();
                #pragma unroll
                for (int v = 0; v < 8; v++) {
                    s1[(v << 8) + tid] = e1[v];       // lane-consecutive -> conflict-free
                    s2[(v << 8) + tid] = e2[v];
                }
                __syncthreads();
                const int pt = tid ^ lm;
                #pragma unroll
                for (int v = 0; v < 8; v++) {
                    float pv = s1[(v << 8) + pt];
                    e1[v] = keepmin ? fminf(e1[v], pv) : fmaxf(e1[v], pv);
                    float qv = s2[(v << 8) + pt];
                    e2[v] = keepmin ? fminf(e2[v], qv) : fmaxf(e2[v], qv);
                }
            }
        }
        // intra-thread j = 4, 2, 1 (dir uniform = up since k >= 8)
        ce_dir(e1[0], e1[4], up); ce_dir(e1[1], e1[5], up);
        ce_dir(e1[2], e1[6], up); ce_dir(e1[3], e1[7], up);
        ce_dir(e2[0], e2[4], up); ce_dir(e2[1], e2[5], up);
        ce_dir(e2[2], e2[6], up); ce_dir(e2[3], e2[7], up);

        ce_dir(e1[0], e1[2], up); ce_dir(e1[1], e1[3], up);
        ce_dir(e1[4], e1[6], up); ce_dir(e1[5], e1[7], up);
        ce_dir(e2[0], e2[2], up); ce_dir(e2[1], e2[3], up);
        ce_dir(e2[4], e2[6], up); ce_dir(e2[5], e2[7], up);

        ce_dir(e1[0], e1[1], up); ce_dir(e1[2], e1[3], up);
        ce_dir(e1[4], e1[5], up); ce_dir(e1[6], e1[7], up);
        ce_dir(e2[0], e2[1], up); ce_dir(e2[2], e2[3], up);
        ce_dir(e2[4], e2[5], up); ce_dir(e2[6], e2[7], up);
    }

    // ---- sum of squared diffs of the two sorted sequences (positions match in-register)
    float lsum = 0.f;
    #pragma unroll
    for (int v = 0; v < 8; v++) {
        float d0 = e1[v] - e2[v];
        lsum += d0 * d0;
    }
    #pragma unroll
    for (int off = 32; off > 0; off >>= 1)
        lsum += __shfl_down(lsum, off, 64);
    int wave = tid >> 6;
    if ((tid & 63) == 0) red[wave] = lsum;
    __syncthreads();
    if (tid == 0) {
        float t = red[0] + red[1] + red[2] + red[3];
        atomicAdd(&ws[b * NSTRIPE + (bid & (NSTRIPE - 1))], t);
    }
}

__global__ void finalize_kernel(const float* __restrict__ ws, float* __restrict__ out) {
    __shared__ float red[256];
    int tid = threadIdx.x;
    for (int b = 0; b < BB; b++) {
        float s = 0.f;
        for (int i = tid; i < NSTRIPE; i += 256) s += ws[b * NSTRIPE + i];
        red[tid] = s;
        __syncthreads();
        for (int o = 128; o > 0; o >>= 1) {
            if (tid < o) red[tid] += red[tid + o];
            __syncthreads();
        }
        if (tid == 0) {
            float swd = red[0] / ((float)NN * (float)PP);
            out[b] = expf(-swd * swd * 0.5f);
        }
        __syncthreads();
    }
}

extern "C" void kernel_launch(void* const* d_in, const int* in_sizes, int n_in,
                              void* d_out, int out_size, void* d_ws, size_t ws_size,
                              hipStream_t stream) {
    const float* x = (const float*)d_in[0];
    const float* y = (const float*)d_in[1];
    const float* proj = (const float*)d_in[2];
    float* out = (float*)d_out;
    float* ws = (float*)d_ws;

    zero_ws_kernel<<<(BB * NSTRIPE + 255) / 256, 256, 0, stream>>>(ws);
    swd_kernel<<<BB * PP, 256, 0, stream>>>(x, y, proj, ws);
    finalize_kernel<<<1, 256, 0, stream>>>(ws, out);
}